// Round 8
// baseline (763.083 us; speedup 1.0000x reference)
//
#include <hip/hip_runtime.h>
#include <hip/hip_bf16.h>

// NGCF forward on MI355X.
// r15: r12 k_layer body, PERSISTENT grid (1024 blocks, grid-stride tiles).
// History:
//  r9  split spmm(75% occ)=95us + dense ~20us                   -> 586 total
//  r10 fused, 51.7KB LDS -> 45% occ, 128us/layer                -> 574
//  r11 lane-owns-row regs: de-coalesced csr + spills            -> 655 REGRESS
//  r12 fused + weights in global (L2): 61% occ, 119us/layer     -> 571 BEST
//  r13 nt hints + two-stream (confounded)                       -> 692 REGRESS
//  r14 hand csr pipeline: spill signature (FETCH+33/WRITE+23MB) -> 691 REGRESS
// r13/r14 lesson (matches guide Common-mistake #5): source-level scheduling
// tricks are neutral-to-negative here; the compiler already fine-schedules.
// r12's real limiter: VGPR32/LDS34.8KB allow 32 waves/CU, but the 1172-block
// grid = 4.58 blocks/CU -> full wave of 1024 at ~100% residency + 148-block
// TAIL at ~14% utilization -> time-avg occ 61%. r15: grid = 1024 (exactly
// 4 resident blocks/CU), each wave grid-strides tg += 8192 over 9375 tiles
// (~9 tiles/wave; degree variance self-averages; no barrier -> waves loop
// independently). k_layer body unchanged from r12 -> bit-identical numerics.
// CSR build (r8/r9): two-level bucket binning with LDS repack, 32-waves/CU
// blocks, int4 edge loads, reservation-atomic latency hidden.

#define N_USER 100000
#define N_ITEM 50000
#define N_NODES 150000
#define NE 4800000
#define D 64
#define BROWS 128
#define NBUCK ((N_NODES + BROWS - 1) / BROWS)  // 1172
#define BCAP 4480                               // per-bucket: mean 4096 + 6 sigma
#define NG (N_NODES / 16)                       // 9375 row-tiles of 16 (exact)
#define LGRID 1024                              // persistent layer grid (4/CU)
#define LWAVES (LGRID * 8)                      // 8192 wave-slots

// two-level binning
#define SUPSH 12                                // super = row >> 12 (4096 rows)
#define NSUP 37
#define SCAP 133120                             // per-super: mean 131072 + ~5.7 sigma
#define STG1 (NSUP * SCAP)                      // 4,925,440 >= NE
#define CH1 4096                                // edges per binning block (32.8KB LDS)
#define B1 ((NE + CH1 - 1) / CH1)               // 1172 level-1 blocks
#define CPS ((SCAP + CH1 - 1) / CH1)            // 33 chunks per super
#define B2 (NSUP * CPS)                         // 1221 level-2 blocks

typedef __hip_bfloat16 bf16;
typedef unsigned short u16;
typedef __attribute__((ext_vector_type(8))) short short8;
typedef __attribute__((ext_vector_type(4))) float float4v;

__device__ __forceinline__ float bits2f(u16 u) {
  return __uint_as_float(((unsigned int)u) << 16);
}
__device__ __forceinline__ u16 f2bits(float x) {
  union { bf16 h; u16 u; } c;
  c.h = __float2bfloat16(x);
  return c.u;
}
__device__ __forceinline__ float loadF(const void* p, long i, int f32) {
  if (f32) return ((const float*)p)[i];
  return bits2f(((const u16*)p)[i]);
}

__global__ void k_zero(int* __restrict__ p, int n) {
  int i = blockIdx.x * blockDim.x + threadIdx.x;
  if (i < n) p[i] = 0;
}

// flag <- 1 if the float buffers are float32, 0 if bf16.
__global__ void k_detect(const u16* __restrict__ ue, int* __restrict__ flag) {
  int bad = 0;
  for (int t = threadIdx.x; t < 512; t += 256) {
    float f = fabsf(bits2f(ue[t]));
    if (!(f < 1e4f)) bad = 1;  // catches NaN/Inf too
  }
  if (bad) atomicOr(flag, 1);
}

// Pre-pack frag-ordered bf16 weights (one block per layer) + combined bias.
// wfrag[layer][f]: f = ((t*4+s2)*64+lane)*8+j maps to W[k][n],
// k = s2*32+(lane>>4)*8+j (in [Wgc;Wbi]), n = t*16+(lane&15).
__global__ void k_prepw(const void* __restrict__ Wgc, const void* __restrict__ bgc,
                        const void* __restrict__ Wbi, const void* __restrict__ bbi,
                        u16* __restrict__ wfrag, float* __restrict__ biasws,
                        const int* __restrict__ flag) {
  int f32 = *flag;
  int layer = blockIdx.x;
  for (int f = threadIdx.x; f < 8192; f += 512) {
    int j = f & 7;
    int lane = (f >> 3) & 63;
    int s2 = (f >> 9) & 3;
    int t = f >> 11;
    int k = s2 * 32 + (lane >> 4) * 8 + j;
    int n = t * 16 + (lane & 15);
    float w = (k < 64) ? loadF(Wgc, (long)layer * 4096 + k * 64 + n, f32)
                       : loadF(Wbi, (long)layer * 4096 + (k - 64) * 64 + n, f32);
    wfrag[layer * 8192 + f] = f2bits(w);
  }
  if (threadIdx.x < 64)
    biasws[layer * 64 + threadIdx.x] =
        loadF(bgc, layer * 64 + threadIdx.x, f32) +
        loadF(bbi, layer * 64 + threadIdx.x, f32);
}

// ego32[N,64] fp32 and egobf[N,64] bf16 <- concat(user_emb, item_emb)
__global__ void k_init(const void* __restrict__ ue, const void* __restrict__ ie,
                       float* __restrict__ ego32, u16* __restrict__ egobf,
                       const int* __restrict__ flag) {
  int f32 = *flag;
  int i4 = (blockIdx.x * blockDim.x + threadIdx.x) * 4;
  if (i4 >= N_NODES * D) return;
  const int UD = N_USER * D;
  float4 v;
  ushort4 b;
  if (f32) {
    const float* s = (i4 < UD) ? ((const float*)ue + i4) : ((const float*)ie + (i4 - UD));
    v = *(const float4*)s;
    b = make_ushort4(f2bits(v.x), f2bits(v.y), f2bits(v.z), f2bits(v.w));
  } else {
    const u16* s = (i4 < UD) ? ((const u16*)ue + i4) : ((const u16*)ie + (i4 - UD));
    b = *(const ushort4*)s;
    v = make_float4(bits2f(b.x), bits2f(b.y), bits2f(b.z), bits2f(b.w));
  }
  *(float4*)(ego32 + i4) = v;
  *(ushort4*)(egobf + i4) = b;
}

// Level 1: bin a CH1-edge chunk into NSUP super-buckets. Scatter into LDS
// (counting-sort order by super), then write each super's run coalesced into
// staged1[super][SCAP]. Entry: (lr12<<18 | col, val_bits), lr12 = row & 4095.
__global__ void __launch_bounds__(512, 8) k_bin1(
    const int* __restrict__ row, const int* __restrict__ col,
    const void* __restrict__ val, int* __restrict__ scnt,
    int2* __restrict__ staged1, const int* __restrict__ flag) {
  __shared__ int2 sbuf[CH1];                 // 32 KB
  __shared__ int hist[NSUP];
  __shared__ int lstart[NSUP];
  __shared__ int gbase[NSUP];
  __shared__ int lcur[NSUP];
  int f32 = *flag;
  int tid = threadIdx.x;
  int e0 = blockIdx.x * CH1;
  int e1 = min(e0 + CH1, NE);               // e1-e0 always a multiple of 4
  if (tid < NSUP) hist[tid] = 0;
  __syncthreads();
  // pass 1: histogram over supers, 4 edges/thread (int4)
  for (int e = e0 + tid * 4; e < e1; e += 512 * 4) {
    int4 r4 = *(const int4*)(row + e);
    atomicAdd(&hist[r4.x >> SUPSH], 1);
    atomicAdd(&hist[r4.y >> SUPSH], 1);
    atomicAdd(&hist[r4.z >> SUPSH], 1);
    atomicAdd(&hist[r4.w >> SUPSH], 1);
  }
  __syncthreads();
  // wave 0: exclusive scan of hist; issue the global reservation atomic into
  // a register (committed to LDS only after the scatter -> latency hidden)
  int resv = 0;
  if (tid < 64) {
    int h = (tid < NSUP) ? hist[tid] : 0;
    int inc = h;
#pragma unroll
    for (int off = 1; off < 64; off <<= 1) {
      int v = __shfl_up(inc, off);
      if (tid >= off) inc += v;
    }
    if (tid < NSUP) {
      int ex = inc - h;
      lstart[tid] = ex;
      lcur[tid] = ex;
      if (h) resv = atomicAdd(&scnt[tid], h);
    }
  }
  __syncthreads();
  // pass 2: scatter into LDS in super-sorted order, 4 edges/thread
  for (int e = e0 + tid * 4; e < e1; e += 512 * 4) {
    int4 r4 = *(const int4*)(row + e);
    int4 c4 = *(const int4*)(col + e);
    int vb[4];
    if (f32) {
      float4 v4 = *(const float4*)((const float*)val + e);
      vb[0] = __float_as_int(v4.x); vb[1] = __float_as_int(v4.y);
      vb[2] = __float_as_int(v4.z); vb[3] = __float_as_int(v4.w);
    } else {
      ushort4 v4 = *(const ushort4*)((const u16*)val + e);
      vb[0] = __float_as_int(bits2f(v4.x)); vb[1] = __float_as_int(bits2f(v4.y));
      vb[2] = __float_as_int(bits2f(v4.z)); vb[3] = __float_as_int(bits2f(v4.w));
    }
    int rr[4] = {r4.x, r4.y, r4.z, r4.w};
    int cc[4] = {c4.x, c4.y, c4.z, c4.w};
#pragma unroll
    for (int j = 0; j < 4; ++j) {
      int s = rr[j] >> SUPSH;
      int pos = atomicAdd(&lcur[s], 1);
      sbuf[pos] = make_int2(((rr[j] & 4095) << 18) | cc[j], vb[j]);
    }
  }
  // commit reservations (atomic result consumed here, after scatter)
  if (tid < NSUP) gbase[tid] = resv;
  __syncthreads();
  // coalesced dense copy of each super's run; waves split the supers
  int wv = tid >> 6;
  int ln = tid & 63;
  for (int s = wv; s < NSUP; s += 8) {
    int h = hist[s];
    int gb = gbase[s];
    int ls = lstart[s];
    if (gb + h > SCAP) h = max(0, SCAP - gb);
    int2* dst = staged1 + (size_t)s * SCAP + gb;
    for (int i = ln; i < h; i += 64) dst[i] = sbuf[ls + i];
  }
}

// Level 2: re-bin one CH1-entry chunk of a super segment into its 32 row-
// buckets (global bucket = super*32 + (lr12>>7)), LDS repack, coalesced dense
// write into staged2[bucket][BCAP]. Output entry: (lr7<<18 | col, val_bits).
__global__ void __launch_bounds__(512, 8) k_bin2(
    const int* __restrict__ scnt, const int2* __restrict__ staged1,
    int* __restrict__ bcnt, int2* __restrict__ staged2) {
  __shared__ int2 sbuf[CH1];                 // 32 KB
  __shared__ int hist[32];
  __shared__ int lstart[32];
  __shared__ int gbase[32];
  __shared__ int lcur[32];
  int tid = threadIdx.x;
  int sup = blockIdx.x / CPS;
  int e0 = (blockIdx.x % CPS) * CH1;
  int n = min(scnt[sup], SCAP);
  int e1 = min(e0 + CH1, n);
  if (e0 >= e1) return;  // uniform across block
  const int2* seg = staged1 + (size_t)sup * SCAP;
  if (tid < 32) hist[tid] = 0;
  __syncthreads();
  // histogram, 2 entries/thread (int4 over int2 pairs); e1 may be odd
  {
    int e = e0 + tid * 2;
    for (; e + 1 < e1; e += 1024) {
      int4 two = *(const int4*)(seg + e);
      atomicAdd(&hist[two.x >> 25], 1);
      atomicAdd(&hist[two.z >> 25], 1);
    }
    if (e < e1) atomicAdd(&hist[seg[e].x >> 25], 1);
  }
  __syncthreads();
  int resv = 0;
  if (tid < 64) {
    int h = (tid < 32) ? hist[tid & 31] : 0;
    int inc = h;
#pragma unroll
    for (int off = 1; off < 32; off <<= 1) {
      int v = __shfl_up(inc, off);
      if (tid >= off) inc += v;
    }
    if (tid < 32) {
      int ex = inc - h;
      lstart[tid] = ex;
      lcur[tid] = ex;
      if (h) resv = atomicAdd(&bcnt[sup * 32 + tid], h);
    }
  }
  __syncthreads();
  // scatter into LDS in bucket-sorted order, 2 entries/thread
  {
    int e = e0 + tid * 2;
    for (; e + 1 < e1; e += 1024) {
      int4 two = *(const int4*)(seg + e);
      int lb0 = two.x >> 25;
      int p0 = atomicAdd(&lcur[lb0], 1);
      sbuf[p0] = make_int2(two.x & 0x01FFFFFF, two.y);
      int lb1 = two.z >> 25;
      int p1 = atomicAdd(&lcur[lb1], 1);
      sbuf[p1] = make_int2(two.z & 0x01FFFFFF, two.w);
    }
    if (e < e1) {
      int2 ent = seg[e];
      int lb = ent.x >> 25;
      int pos = atomicAdd(&lcur[lb], 1);
      sbuf[pos] = make_int2(ent.x & 0x01FFFFFF, ent.y);
    }
  }
  if (tid < 32) gbase[tid] = resv;
  __syncthreads();
  // coalesced dense copy of each bucket's run; waves split the buckets
  int wv = tid >> 6;
  int ln = tid & 63;
  for (int lb = wv; lb < 32; lb += 8) {
    int h = hist[lb];
    int gb = gbase[lb];
    int ls = lstart[lb];
    int b = sup * 32 + lb;
    if (b >= NBUCK) continue;       // unreachable given row bounds; safety
    if (gb + h > BCAP) h = max(0, BCAP - gb);
    int2* dst = staged2 + (size_t)b * BCAP + gb;
    for (int i = ln; i < h; i += 64) dst[i] = sbuf[ls + i];
  }
}

// Exclusive scan of per-bucket totals -> bbase[NBUCK]. One block of 1024.
__global__ void __launch_bounds__(1024) k_bucketbase(const int* __restrict__ bcnt,
                                                     int* __restrict__ bbase) {
  __shared__ int sh[2048];
  int tid = threadIdx.x;
  int t0 = (tid < NBUCK) ? min(bcnt[tid], BCAP) : 0;
  int i1 = 1024 + tid;
  int t1 = (i1 < NBUCK) ? min(bcnt[i1], BCAP) : 0;
  sh[tid] = t0;
  sh[i1] = t1;
  __syncthreads();
  for (int off = 1; off < 2048; off <<= 1) {
    int a0 = (tid >= off) ? sh[tid - off] : 0;
    int a1 = (i1 >= off) ? sh[i1 - off] : 0;
    __syncthreads();
    sh[tid] += a0;
    sh[i1] += a1;
    __syncthreads();
  }
  if (tid < NBUCK) bbase[tid] = sh[tid] - t0;       // exclusive
  if (i1 < NBUCK) bbase[i1] = sh[i1] - t1;
}

// One block per bucket: LDS counting sort of the bucket's staged edges, then
// coalesced sequential write of the contiguous CSR segment + rp.
__global__ void __launch_bounds__(512, 8) k_sortbucket(
    const int* __restrict__ bcnt, const int2* __restrict__ staged,
    const int* __restrict__ bbase, int* __restrict__ rp, int2* __restrict__ csr) {
  __shared__ int2 sbuf[BCAP];      // 35.8 KB
  __shared__ int hist[BROWS];
  __shared__ int cursor[BROWS];
  __shared__ int scantmp[BROWS];
  int tid = threadIdx.x;
  int b = blockIdx.x;
  if (tid < BROWS) hist[tid] = 0;
  __syncthreads();

  int n = min(bcnt[b], BCAP);
  const int2* seg = staged + (size_t)b * BCAP;
  {
    int e = tid * 2;
    for (; e + 1 < n; e += 1024) {
      int4 two = *(const int4*)(seg + e);
      atomicAdd(&hist[two.x >> 18], 1);
      atomicAdd(&hist[two.z >> 18], 1);
    }
    if (e < n) atomicAdd(&hist[seg[e].x >> 18], 1);
  }
  __syncthreads();

  if (tid < BROWS) scantmp[tid] = hist[tid];
  __syncthreads();
  for (int off = 1; off < BROWS; off <<= 1) {
    int v = (tid < BROWS && tid >= off) ? scantmp[tid - off] : 0;
    __syncthreads();
    if (tid < BROWS) scantmp[tid] += v;   // inclusive
    __syncthreads();
  }
  int base_b = bbase[b];
  if (tid < BROWS) {
    int ex = scantmp[tid] - hist[tid];    // exclusive start within bucket
    cursor[tid] = ex;
    int r = b * BROWS + tid;
    if (r < N_NODES) rp[r] = base_b + ex;
  }
  if (b == 0 && tid == 0) rp[N_NODES] = NE;
  __syncthreads();

  {
    int e = tid * 2;
    for (; e + 1 < n; e += 1024) {
      int4 two = *(const int4*)(seg + e);
      int lr0 = two.x >> 18;
      int p0 = atomicAdd(&cursor[lr0], 1);
      if (p0 < BCAP) sbuf[p0] = make_int2(two.x & 0x3FFFF, two.y);
      int lr1 = two.z >> 18;
      int p1 = atomicAdd(&cursor[lr1], 1);
      if (p1 < BCAP) sbuf[p1] = make_int2(two.z & 0x3FFFF, two.w);
    }
    if (e < n) {
      int2 ent = seg[e];
      int lr = ent.x >> 18;
      int pos = atomicAdd(&cursor[lr], 1);
      if (pos < BCAP) sbuf[pos] = make_int2(ent.x & 0x3FFFF, ent.y);
    }
  }
  __syncthreads();

  int tot = min(scantmp[BROWS - 1], BCAP);
  for (int i = tid; i < tot; i += 512) csr[(size_t)base_b + i] = sbuf[i];
}

// FUSED layer (r15 = r12 body, persistent grid). Per wave, per tile: (phase
// 1) quarter-wave register SpMM for 16 rows (4 passes; 16 lanes consume full
// 128B neighbor rows, csr broadcast within quarter-wave), depositing bf16
// [side|prod] into a wave-private LDS tile (272B row stride -> <=2-way bank
// aliasing, free); (phase 2) 16x16x32 bf16 MFMA, B-frags read as coalesced
// 16B GLOBAL loads from the pre-packed L2-resident wfrag. No barrier -> each
// wave grid-strides tiles independently (grid=1024 = exactly 4 resident
// blocks/CU, no tail; ~9 tiles/wave self-averages degree variance).
// Inputs read-only, outputs write-only (ping-pong). Bit-identical to r12.
__global__ void __launch_bounds__(512, 8) k_layer(
    const int* __restrict__ rp, const int2* __restrict__ csr,
    const u16* __restrict__ egobf_i, const float* __restrict__ ego32_i,
    const u16* __restrict__ wfrag, const float* __restrict__ biasws,
    float* __restrict__ ego32_o, u16* __restrict__ egobf_o, int layer) {
  __shared__ u16 tiles[8][2176];   // 8 waves x 16 rows x 136 u16 (272B stride)
  int tid = threadIdx.x;
  int lane = tid & 63;
  int ln = lane & 15;
  int quad = lane >> 4;            // 0..3
  int wv = tid >> 6;               // 0..7
  u16* tile = &tiles[wv][0];
  const u16* wf = wfrag + layer * 8192;
  const float* bi = biasws + layer * 64;

#pragma unroll 1
  for (int tg = blockIdx.x * 8 + wv; tg < NG; tg += LWAVES) {
    // ---- phase 1: SpMM for 16 rows, quarter-wave per row, 4 passes ----
#pragma unroll 1
    for (int p = 0; p < 4; ++p) {
      int r = tg * 16 + p * 4 + quad;
      int s = rp[r];
      int e = rp[r + 1];
      float4 acc = make_float4(0.f, 0.f, 0.f, 0.f);
      int i = s;
      for (; i + 8 <= e; i += 8) {
        int2 cc[8];
#pragma unroll
        for (int t = 0; t < 8; ++t) cc[t] = csr[i + t];
        ushort4 gg[8];
#pragma unroll
        for (int t = 0; t < 8; ++t)
          gg[t] = *(const ushort4*)(egobf_i + (size_t)cc[t].x * 64 + ln * 4);
#pragma unroll
        for (int t = 0; t < 8; ++t) {
          float v = __int_as_float(cc[t].y);
          acc.x += v * bits2f(gg[t].x);
          acc.y += v * bits2f(gg[t].y);
          acc.z += v * bits2f(gg[t].z);
          acc.w += v * bits2f(gg[t].w);
        }
      }
      for (; i < e; ++i) {
        int2 c = csr[i];
        ushort4 g = *(const ushort4*)(egobf_i + (size_t)c.x * 64 + ln * 4);
        float v = __int_as_float(c.y);
        acc.x += v * bits2f(g.x);
        acc.y += v * bits2f(g.y);
        acc.z += v * bits2f(g.z);
        acc.w += v * bits2f(g.w);
      }
      float4 er = *(const float4*)(ego32_i + (size_t)r * 64 + ln * 4);
      // deposit [side|prod] into wave-private LDS tile row (p*4+quad)
      u16* trow = tile + (p * 4 + quad) * 136;
      *(ushort4*)(trow + ln * 4) =
          make_ushort4(f2bits(acc.x), f2bits(acc.y), f2bits(acc.z), f2bits(acc.w));
      *(ushort4*)(trow + 64 + ln * 4) =
          make_ushort4(f2bits(er.x * acc.x), f2bits(er.y * acc.y),
                       f2bits(er.z * acc.z), f2bits(er.w * acc.w));
    }
    // wave-local ds ordering via lgkmcnt; tile is wave-private -> no barrier

    // ---- phase 2: MFMA 16 rows x 128K x 64N; B-frags from global (L2) ----
    float4v acc2[4];
#pragma unroll
    for (int t = 0; t < 4; ++t) acc2[t] = (float4v){0.f, 0.f, 0.f, 0.f};
#pragma unroll
    for (int s2 = 0; s2 < 4; ++s2) {
      short8 A = *(const short8*)(tile + (size_t)ln * 136 + s2 * 32 + quad * 8);
#pragma unroll
      for (int t = 0; t < 4; ++t) {
        short8 Bf = *(const short8*)(wf + ((size_t)((t * 4 + s2) * 64 + lane)) * 8);
        acc2[t] = __builtin_amdgcn_mfma_f32_16x16x32_bf16(A, Bf, acc2[t], 0, 0, 0);
      }
    }
    int r0 = tg * 16;
#pragma unroll
    for (int t = 0; t < 4; ++t) {
      float bt = bi[t * 16 + ln];
#pragma unroll
      for (int g2 = 0; g2 < 4; ++g2) {
        float x = acc2[t][g2] + bt;
        x = fmaxf(x, 0.2f * x);  // leaky_relu(0.2)
        size_t idx = (size_t)(r0 + quad * 4 + g2) * 64 + t * 16 + ln;
        ego32_o[idx] = x;
        egobf_o[idx] = f2bits(x);
      }
    }
  }
}

// gather 8192 output rows into out slice; optional l2-normalize per row.
__global__ void k_gather(const float* __restrict__ ego, const int* __restrict__ users,
                         const int* __restrict__ items, void* __restrict__ out,
                         int slice, int do_norm, const int* __restrict__ flag) {
  int f32 = *flag;
  int b = blockIdx.x * 4 + (threadIdx.x >> 6);
  int lane = threadIdx.x & 63;
  if (b >= 8192) return;
  int r = (b < 4096) ? users[b] : (N_USER + items[b - 4096]);
  float x = ego[(size_t)r * D + lane];
  float scale = 1.f;
  if (do_norm) {
    float ss = x * x;
    for (int off = 32; off > 0; off >>= 1) ss += __shfl_xor(ss, off);
    scale = 1.f / fmaxf(sqrtf(ss), 1e-12f);
  }
  float y = x * scale;
  long idx = (long)b * 256 + slice * 64 + lane;
  if (f32) ((float*)out)[idx] = y;
  else ((bf16*)out)[idx] = __float2bfloat16(y);
}

extern "C" void kernel_launch(void* const* d_in, const int* in_sizes, int n_in,
                              void* d_out, int out_size, void* d_ws, size_t ws_size,
                              hipStream_t stream) {
  const void* ue = d_in[0];
  const void* ie = d_in[1];
  const void* Wgc = d_in[2];
  const void* bgc = d_in[3];
  const void* Wbi = d_in[4];
  const void* bbi = d_in[5];
  const void* aval = d_in[6];
  const int* arow = (const int*)d_in[7];
  const int* acol = (const int*)d_in[8];
  const int* users = (const int*)d_in[9];
  const int* items = (const int*)d_in[10];

  char* ws = (char*)d_ws;
  size_t off = 0;
  float* ego32a = (float*)(ws + off); off += (size_t)N_NODES * D * 4;     // 38.4 MB
  u16* egobfa = (u16*)(ws + off);     off += (size_t)N_NODES * D * 2;     // 19.2 MB
  float* ego32b = (float*)(ws + off); off += (size_t)N_NODES * D * 4;     // 38.4 MB
  u16* egobfb = (u16*)(ws + off);     off += (size_t)N_NODES * D * 2;     // 19.2 MB
  int2* staged = (int2*)(ws + off);   off += (size_t)NBUCK * BCAP * 8;    // 42.0 MB
  int2* csr = (int2*)(ws + off);      off += (size_t)STG1 * 8;            // 39.4 MB (aliases level-1 staging)
  int* rp = (int*)(ws + off);         off += (size_t)(N_NODES + 64) * 4;
  int* bcnt = (int*)(ws + off);       off += (size_t)NBUCK * 4;
  int* scnt = (int*)(ws + off);       off += 64 * 4;                      // contiguous after bcnt
  int* bbase = (int*)(ws + off);      off += (size_t)(NBUCK + 64) * 4;
  int* flag = (int*)(ws + off);       off += 256;
  u16* wfrag = (u16*)(ws + off);      off += 3 * 8192 * 2;                // 48 KB frag-ordered weights
  float* biasws = (float*)(ws + off); off += 3 * 64 * 4;                  // combined bias
  int2* staged1 = csr;                // level-1 staging aliases csr (dead until sortbucket)
  (void)ws_size;

  k_zero<<<1, 64, 0, stream>>>(flag, 1);
  k_detect<<<1, 256, 0, stream>>>((const u16*)ue, flag);
  k_zero<<<(NBUCK + 64 + 255) / 256, 256, 0, stream>>>(bcnt, NBUCK + 64);  // bcnt + scnt
  k_prepw<<<3, 512, 0, stream>>>(Wgc, bgc, Wbi, bbi, wfrag, biasws, flag);
  k_init<<<(N_NODES * D / 4 + 255) / 256, 256, 0, stream>>>(ue, ie, ego32a, egobfa, flag);
  // slice 0 = raw (un-normalized) initial ego
  k_gather<<<2048, 256, 0, stream>>>(ego32a, users, items, d_out, 0, 0, flag);
  k_bin1<<<B1, 512, 0, stream>>>(arow, acol, aval, scnt, staged1, flag);
  k_bin2<<<B2, 512, 0, stream>>>(scnt, staged1, bcnt, staged);
  k_bucketbase<<<1, 1024, 0, stream>>>(bcnt, bbase);
  k_sortbucket<<<NBUCK, 512, 0, stream>>>(bcnt, staged, bbase, rp, csr);

  float* ei32 = ego32a; u16* eibf = egobfa;
  float* eo32 = ego32b; u16* eobf = egobfb;
  for (int k = 0; k < 3; ++k) {
    k_layer<<<LGRID, 512, 0, stream>>>(rp, csr, eibf, ei32, wfrag, biasws,
                                       eo32, eobf, k);
    k_gather<<<2048, 256, 0, stream>>>(eo32, users, items, d_out, k + 1, 1, flag);
    float* t32 = ei32; ei32 = eo32; eo32 = t32;
    u16* tbf = eibf; eibf = eobf; eobf = tbf;
  }
}

// Round 9
// 527.241 us; speedup vs baseline: 1.4473x; 1.4473x over previous
//
#include <hip/hip_runtime.h>
#include <hip/hip_bf16.h>

// NGCF forward on MI355X.
// r16: FINE-GRAINED k_layer — 1 tile per 4-wave block. History:
//  r12 fused, weights in global L2, 1 tile/wave, grid 1172x512  -> 571 BEST (119us/layer)
//  r13 nt hints + two-stream                                    -> 692 REGRESS
//  r14 hand csr pipeline (spill: FETCH+33/WRITE+23MB)           -> 691 REGRESS
//  r15 persistent grid-stride (spill again: FETCH+76/WRITE+113;
//      and the tile-granularity bound makes 2 rounds inevitable)-> 763 REGRESS
// Scheduling-bound analysis: with unit = 1 tile/wave, capacity = 8192
// resident wave-slots vs 9375 tiles -> makespan >= 2 x T_tile(~60us) for ANY
// schedule; r12's 119us sits AT that bound. Fix = smaller quantum, not a
// different schedule: r16 splits a tile across a 4-wave 256-thread block.
// Wave wv runs ONE SpMM pass (4 rows; inner loop byte-identical to r12),
// deposits into a block-shared LDS tile (4.4KB), __syncthreads, then each
// wave computes only its own t=wv column-slice MFMA (4 MFMAs, A-frags
// broadcast from LDS) and writes cols [wv*16,+16). Unit time ~T_tile/4,
// grid = 9375 one-tile blocks, capacity 8 blocks/CU -> ~4.6 fine rounds.
// No persistent loop -> no spill risk. Per-row edge order unchanged ->
// bit-identical numerics to r12.
// CSR build (r8/r9): two-level bucket binning with LDS repack, 32-waves/CU
// blocks, int4 edge loads, reservation-atomic latency hidden.

#define N_USER 100000
#define N_ITEM 50000
#define N_NODES 150000
#define NE 4800000
#define D 64
#define BROWS 128
#define NBUCK ((N_NODES + BROWS - 1) / BROWS)  // 1172
#define BCAP 4480                               // per-bucket: mean 4096 + 6 sigma
#define NG (N_NODES / 16)                       // 9375 row-tiles of 16 (exact)

// two-level binning
#define SUPSH 12                                // super = row >> 12 (4096 rows)
#define NSUP 37
#define SCAP 133120                             // per-super: mean 131072 + ~5.7 sigma
#define STG1 (NSUP * SCAP)                      // 4,925,440 >= NE
#define CH1 4096                                // edges per binning block (32.8KB LDS)
#define B1 ((NE + CH1 - 1) / CH1)               // 1172 level-1 blocks
#define CPS ((SCAP + CH1 - 1) / CH1)            // 33 chunks per super
#define B2 (NSUP * CPS)                         // 1221 level-2 blocks

typedef __hip_bfloat16 bf16;
typedef unsigned short u16;
typedef __attribute__((ext_vector_type(8))) short short8;
typedef __attribute__((ext_vector_type(4))) float float4v;

__device__ __forceinline__ float bits2f(u16 u) {
  return __uint_as_float(((unsigned int)u) << 16);
}
__device__ __forceinline__ u16 f2bits(float x) {
  union { bf16 h; u16 u; } c;
  c.h = __float2bfloat16(x);
  return c.u;
}
__device__ __forceinline__ float loadF(const void* p, long i, int f32) {
  if (f32) return ((const float*)p)[i];
  return bits2f(((const u16*)p)[i]);
}

__global__ void k_zero(int* __restrict__ p, int n) {
  int i = blockIdx.x * blockDim.x + threadIdx.x;
  if (i < n) p[i] = 0;
}

// flag <- 1 if the float buffers are float32, 0 if bf16.
__global__ void k_detect(const u16* __restrict__ ue, int* __restrict__ flag) {
  int bad = 0;
  for (int t = threadIdx.x; t < 512; t += 256) {
    float f = fabsf(bits2f(ue[t]));
    if (!(f < 1e4f)) bad = 1;  // catches NaN/Inf too
  }
  if (bad) atomicOr(flag, 1);
}

// Pre-pack frag-ordered bf16 weights (one block per layer) + combined bias.
// wfrag[layer][f]: f = ((t*4+s2)*64+lane)*8+j maps to W[k][n],
// k = s2*32+(lane>>4)*8+j (in [Wgc;Wbi]), n = t*16+(lane&15).
__global__ void k_prepw(const void* __restrict__ Wgc, const void* __restrict__ bgc,
                        const void* __restrict__ Wbi, const void* __restrict__ bbi,
                        u16* __restrict__ wfrag, float* __restrict__ biasws,
                        const int* __restrict__ flag) {
  int f32 = *flag;
  int layer = blockIdx.x;
  for (int f = threadIdx.x; f < 8192; f += 512) {
    int j = f & 7;
    int lane = (f >> 3) & 63;
    int s2 = (f >> 9) & 3;
    int t = f >> 11;
    int k = s2 * 32 + (lane >> 4) * 8 + j;
    int n = t * 16 + (lane & 15);
    float w = (k < 64) ? loadF(Wgc, (long)layer * 4096 + k * 64 + n, f32)
                       : loadF(Wbi, (long)layer * 4096 + (k - 64) * 64 + n, f32);
    wfrag[layer * 8192 + f] = f2bits(w);
  }
  if (threadIdx.x < 64)
    biasws[layer * 64 + threadIdx.x] =
        loadF(bgc, layer * 64 + threadIdx.x, f32) +
        loadF(bbi, layer * 64 + threadIdx.x, f32);
}

// ego32[N,64] fp32 and egobf[N,64] bf16 <- concat(user_emb, item_emb)
__global__ void k_init(const void* __restrict__ ue, const void* __restrict__ ie,
                       float* __restrict__ ego32, u16* __restrict__ egobf,
                       const int* __restrict__ flag) {
  int f32 = *flag;
  int i4 = (blockIdx.x * blockDim.x + threadIdx.x) * 4;
  if (i4 >= N_NODES * D) return;
  const int UD = N_USER * D;
  float4 v;
  ushort4 b;
  if (f32) {
    const float* s = (i4 < UD) ? ((const float*)ue + i4) : ((const float*)ie + (i4 - UD));
    v = *(const float4*)s;
    b = make_ushort4(f2bits(v.x), f2bits(v.y), f2bits(v.z), f2bits(v.w));
  } else {
    const u16* s = (i4 < UD) ? ((const u16*)ue + i4) : ((const u16*)ie + (i4 - UD));
    b = *(const ushort4*)s;
    v = make_float4(bits2f(b.x), bits2f(b.y), bits2f(b.z), bits2f(b.w));
  }
  *(float4*)(ego32 + i4) = v;
  *(ushort4*)(egobf + i4) = b;
}

// Level 1: bin a CH1-edge chunk into NSUP super-buckets. Scatter into LDS
// (counting-sort order by super), then write each super's run coalesced into
// staged1[super][SCAP]. Entry: (lr12<<18 | col, val_bits), lr12 = row & 4095.
__global__ void __launch_bounds__(512, 8) k_bin1(
    const int* __restrict__ row, const int* __restrict__ col,
    const void* __restrict__ val, int* __restrict__ scnt,
    int2* __restrict__ staged1, const int* __restrict__ flag) {
  __shared__ int2 sbuf[CH1];                 // 32 KB
  __shared__ int hist[NSUP];
  __shared__ int lstart[NSUP];
  __shared__ int gbase[NSUP];
  __shared__ int lcur[NSUP];
  int f32 = *flag;
  int tid = threadIdx.x;
  int e0 = blockIdx.x * CH1;
  int e1 = min(e0 + CH1, NE);               // e1-e0 always a multiple of 4
  if (tid < NSUP) hist[tid] = 0;
  __syncthreads();
  // pass 1: histogram over supers, 4 edges/thread (int4)
  for (int e = e0 + tid * 4; e < e1; e += 512 * 4) {
    int4 r4 = *(const int4*)(row + e);
    atomicAdd(&hist[r4.x >> SUPSH], 1);
    atomicAdd(&hist[r4.y >> SUPSH], 1);
    atomicAdd(&hist[r4.z >> SUPSH], 1);
    atomicAdd(&hist[r4.w >> SUPSH], 1);
  }
  __syncthreads();
  // wave 0: exclusive scan of hist; issue the global reservation atomic into
  // a register (committed to LDS only after the scatter -> latency hidden)
  int resv = 0;
  if (tid < 64) {
    int h = (tid < NSUP) ? hist[tid] : 0;
    int inc = h;
#pragma unroll
    for (int off = 1; off < 64; off <<= 1) {
      int v = __shfl_up(inc, off);
      if (tid >= off) inc += v;
    }
    if (tid < NSUP) {
      int ex = inc - h;
      lstart[tid] = ex;
      lcur[tid] = ex;
      if (h) resv = atomicAdd(&scnt[tid], h);
    }
  }
  __syncthreads();
  // pass 2: scatter into LDS in super-sorted order, 4 edges/thread
  for (int e = e0 + tid * 4; e < e1; e += 512 * 4) {
    int4 r4 = *(const int4*)(row + e);
    int4 c4 = *(const int4*)(col + e);
    int vb[4];
    if (f32) {
      float4 v4 = *(const float4*)((const float*)val + e);
      vb[0] = __float_as_int(v4.x); vb[1] = __float_as_int(v4.y);
      vb[2] = __float_as_int(v4.z); vb[3] = __float_as_int(v4.w);
    } else {
      ushort4 v4 = *(const ushort4*)((const u16*)val + e);
      vb[0] = __float_as_int(bits2f(v4.x)); vb[1] = __float_as_int(bits2f(v4.y));
      vb[2] = __float_as_int(bits2f(v4.z)); vb[3] = __float_as_int(bits2f(v4.w));
    }
    int rr[4] = {r4.x, r4.y, r4.z, r4.w};
    int cc[4] = {c4.x, c4.y, c4.z, c4.w};
#pragma unroll
    for (int j = 0; j < 4; ++j) {
      int s = rr[j] >> SUPSH;
      int pos = atomicAdd(&lcur[s], 1);
      sbuf[pos] = make_int2(((rr[j] & 4095) << 18) | cc[j], vb[j]);
    }
  }
  // commit reservations (atomic result consumed here, after scatter)
  if (tid < NSUP) gbase[tid] = resv;
  __syncthreads();
  // coalesced dense copy of each super's run; waves split the supers
  int wv = tid >> 6;
  int ln = tid & 63;
  for (int s = wv; s < NSUP; s += 8) {
    int h = hist[s];
    int gb = gbase[s];
    int ls = lstart[s];
    if (gb + h > SCAP) h = max(0, SCAP - gb);
    int2* dst = staged1 + (size_t)s * SCAP + gb;
    for (int i = ln; i < h; i += 64) dst[i] = sbuf[ls + i];
  }
}

// Level 2: re-bin one CH1-entry chunk of a super segment into its 32 row-
// buckets (global bucket = super*32 + (lr12>>7)), LDS repack, coalesced dense
// write into staged2[bucket][BCAP]. Output entry: (lr7<<18 | col, val_bits).
__global__ void __launch_bounds__(512, 8) k_bin2(
    const int* __restrict__ scnt, const int2* __restrict__ staged1,
    int* __restrict__ bcnt, int2* __restrict__ staged2) {
  __shared__ int2 sbuf[CH1];                 // 32 KB
  __shared__ int hist[32];
  __shared__ int lstart[32];
  __shared__ int gbase[32];
  __shared__ int lcur[32];
  int tid = threadIdx.x;
  int sup = blockIdx.x / CPS;
  int e0 = (blockIdx.x % CPS) * CH1;
  int n = min(scnt[sup], SCAP);
  int e1 = min(e0 + CH1, n);
  if (e0 >= e1) return;  // uniform across block
  const int2* seg = staged1 + (size_t)sup * SCAP;
  if (tid < 32) hist[tid] = 0;
  __syncthreads();
  // histogram, 2 entries/thread (int4 over int2 pairs); e1 may be odd
  {
    int e = e0 + tid * 2;
    for (; e + 1 < e1; e += 1024) {
      int4 two = *(const int4*)(seg + e);
      atomicAdd(&hist[two.x >> 25], 1);
      atomicAdd(&hist[two.z >> 25], 1);
    }
    if (e < e1) atomicAdd(&hist[seg[e].x >> 25], 1);
  }
  __syncthreads();
  int resv = 0;
  if (tid < 64) {
    int h = (tid < 32) ? hist[tid & 31] : 0;
    int inc = h;
#pragma unroll
    for (int off = 1; off < 32; off <<= 1) {
      int v = __shfl_up(inc, off);
      if (tid >= off) inc += v;
    }
    if (tid < 32) {
      int ex = inc - h;
      lstart[tid] = ex;
      lcur[tid] = ex;
      if (h) resv = atomicAdd(&bcnt[sup * 32 + tid], h);
    }
  }
  __syncthreads();
  // scatter into LDS in bucket-sorted order, 2 entries/thread
  {
    int e = e0 + tid * 2;
    for (; e + 1 < e1; e += 1024) {
      int4 two = *(const int4*)(seg + e);
      int lb0 = two.x >> 25;
      int p0 = atomicAdd(&lcur[lb0], 1);
      sbuf[p0] = make_int2(two.x & 0x01FFFFFF, two.y);
      int lb1 = two.z >> 25;
      int p1 = atomicAdd(&lcur[lb1], 1);
      sbuf[p1] = make_int2(two.z & 0x01FFFFFF, two.w);
    }
    if (e < e1) {
      int2 ent = seg[e];
      int lb = ent.x >> 25;
      int pos = atomicAdd(&lcur[lb], 1);
      sbuf[pos] = make_int2(ent.x & 0x01FFFFFF, ent.y);
    }
  }
  if (tid < 32) gbase[tid] = resv;
  __syncthreads();
  // coalesced dense copy of each bucket's run; waves split the buckets
  int wv = tid >> 6;
  int ln = tid & 63;
  for (int lb = wv; lb < 32; lb += 8) {
    int h = hist[lb];
    int gb = gbase[lb];
    int ls = lstart[lb];
    int b = sup * 32 + lb;
    if (b >= NBUCK) continue;       // unreachable given row bounds; safety
    if (gb + h > BCAP) h = max(0, BCAP - gb);
    int2* dst = staged2 + (size_t)b * BCAP + gb;
    for (int i = ln; i < h; i += 64) dst[i] = sbuf[ls + i];
  }
}

// Exclusive scan of per-bucket totals -> bbase[NBUCK]. One block of 1024.
__global__ void __launch_bounds__(1024) k_bucketbase(const int* __restrict__ bcnt,
                                                     int* __restrict__ bbase) {
  __shared__ int sh[2048];
  int tid = threadIdx.x;
  int t0 = (tid < NBUCK) ? min(bcnt[tid], BCAP) : 0;
  int i1 = 1024 + tid;
  int t1 = (i1 < NBUCK) ? min(bcnt[i1], BCAP) : 0;
  sh[tid] = t0;
  sh[i1] = t1;
  __syncthreads();
  for (int off = 1; off < 2048; off <<= 1) {
    int a0 = (tid >= off) ? sh[tid - off] : 0;
    int a1 = (i1 >= off) ? sh[i1 - off] : 0;
    __syncthreads();
    sh[tid] += a0;
    sh[i1] += a1;
    __syncthreads();
  }
  if (tid < NBUCK) bbase[tid] = sh[tid] - t0;       // exclusive
  if (i1 < NBUCK) bbase[i1] = sh[i1] - t1;
}

// One block per bucket: LDS counting sort of the bucket's staged edges, then
// coalesced sequential write of the contiguous CSR segment + rp.
__global__ void __launch_bounds__(512, 8) k_sortbucket(
    const int* __restrict__ bcnt, const int2* __restrict__ staged,
    const int* __restrict__ bbase, int* __restrict__ rp, int2* __restrict__ csr) {
  __shared__ int2 sbuf[BCAP];      // 35.8 KB
  __shared__ int hist[BROWS];
  __shared__ int cursor[BROWS];
  __shared__ int scantmp[BROWS];
  int tid = threadIdx.x;
  int b = blockIdx.x;
  if (tid < BROWS) hist[tid] = 0;
  __syncthreads();

  int n = min(bcnt[b], BCAP);
  const int2* seg = staged + (size_t)b * BCAP;
  {
    int e = tid * 2;
    for (; e + 1 < n; e += 1024) {
      int4 two = *(const int4*)(seg + e);
      atomicAdd(&hist[two.x >> 18], 1);
      atomicAdd(&hist[two.z >> 18], 1);
    }
    if (e < n) atomicAdd(&hist[seg[e].x >> 18], 1);
  }
  __syncthreads();

  if (tid < BROWS) scantmp[tid] = hist[tid];
  __syncthreads();
  for (int off = 1; off < BROWS; off <<= 1) {
    int v = (tid < BROWS && tid >= off) ? scantmp[tid - off] : 0;
    __syncthreads();
    if (tid < BROWS) scantmp[tid] += v;   // inclusive
    __syncthreads();
  }
  int base_b = bbase[b];
  if (tid < BROWS) {
    int ex = scantmp[tid] - hist[tid];    // exclusive start within bucket
    cursor[tid] = ex;
    int r = b * BROWS + tid;
    if (r < N_NODES) rp[r] = base_b + ex;
  }
  if (b == 0 && tid == 0) rp[N_NODES] = NE;
  __syncthreads();

  {
    int e = tid * 2;
    for (; e + 1 < n; e += 1024) {
      int4 two = *(const int4*)(seg + e);
      int lr0 = two.x >> 18;
      int p0 = atomicAdd(&cursor[lr0], 1);
      if (p0 < BCAP) sbuf[p0] = make_int2(two.x & 0x3FFFF, two.y);
      int lr1 = two.z >> 18;
      int p1 = atomicAdd(&cursor[lr1], 1);
      if (p1 < BCAP) sbuf[p1] = make_int2(two.z & 0x3FFFF, two.w);
    }
    if (e < n) {
      int2 ent = seg[e];
      int lr = ent.x >> 18;
      int pos = atomicAdd(&cursor[lr], 1);
      if (pos < BCAP) sbuf[pos] = make_int2(ent.x & 0x3FFFF, ent.y);
    }
  }
  __syncthreads();

  int tot = min(scantmp[BROWS - 1], BCAP);
  for (int i = tid; i < tot; i += 512) csr[(size_t)base_b + i] = sbuf[i];
}

// FUSED layer (r16): ONE 16-row tile per 4-wave 256-thread block. Wave wv
// runs SpMM pass p=wv (rows tg*16 + wv*4 + quad; inner loop identical to
// r12: 16 lanes consume full 128B neighbor rows, csr broadcast within
// quarter-wave), depositing bf16 [side|prod] into the block-shared LDS tile
// (272B row stride -> <=2-way bank alias, free). __syncthreads. Then wave wv
// computes ONLY its t=wv column-slice: 4 MFMAs (A-frags broadcast from LDS,
// B-frags 4x16B global loads from L2-resident wfrag) and writes cols
// [wv*16, wv*16+16) of all 16 rows. Fine scheduling quantum (~T_tile/4)
// breaks r12's 2-round tile-granularity bound. Bit-identical numerics.
__global__ void __launch_bounds__(256, 8) k_layer(
    const int* __restrict__ rp, const int2* __restrict__ csr,
    const u16* __restrict__ egobf_i, const float* __restrict__ ego32_i,
    const u16* __restrict__ wfrag, const float* __restrict__ biasws,
    float* __restrict__ ego32_o, u16* __restrict__ egobf_o, int layer) {
  __shared__ u16 tile[2176];       // 16 rows x 136 u16 (272B stride), 4.25KB
  int tid = threadIdx.x;
  int lane = tid & 63;
  int ln = lane & 15;
  int quad = lane >> 4;            // 0..3
  int wv = tid >> 6;               // 0..3 = SpMM pass index = MFMA t-slice
  int tg = blockIdx.x;             // tile index (16 rows); grid == NG
  const u16* wf = wfrag + layer * 8192;

  // ---- phase 1: SpMM pass wv (4 rows, quarter-wave per row) ----
  {
    int r = tg * 16 + wv * 4 + quad;
    int s = rp[r];
    int e = rp[r + 1];
    float4 acc = make_float4(0.f, 0.f, 0.f, 0.f);
    int i = s;
    for (; i + 8 <= e; i += 8) {
      int2 cc[8];
#pragma unroll
      for (int t = 0; t < 8; ++t) cc[t] = csr[i + t];
      ushort4 gg[8];
#pragma unroll
      for (int t = 0; t < 8; ++t)
        gg[t] = *(const ushort4*)(egobf_i + (size_t)cc[t].x * 64 + ln * 4);
#pragma unroll
      for (int t = 0; t < 8; ++t) {
        float v = __int_as_float(cc[t].y);
        acc.x += v * bits2f(gg[t].x);
        acc.y += v * bits2f(gg[t].y);
        acc.z += v * bits2f(gg[t].z);
        acc.w += v * bits2f(gg[t].w);
      }
    }
    for (; i < e; ++i) {
      int2 c = csr[i];
      ushort4 g = *(const ushort4*)(egobf_i + (size_t)c.x * 64 + ln * 4);
      float v = __int_as_float(c.y);
      acc.x += v * bits2f(g.x);
      acc.y += v * bits2f(g.y);
      acc.z += v * bits2f(g.z);
      acc.w += v * bits2f(g.w);
    }
    float4 er = *(const float4*)(ego32_i + (size_t)r * 64 + ln * 4);
    // deposit [side|prod] into shared tile row (wv*4+quad)
    u16* trow = tile + (wv * 4 + quad) * 136;
    *(ushort4*)(trow + ln * 4) =
        make_ushort4(f2bits(acc.x), f2bits(acc.y), f2bits(acc.z), f2bits(acc.w));
    *(ushort4*)(trow + 64 + ln * 4) =
        make_ushort4(f2bits(er.x * acc.x), f2bits(er.y * acc.y),
                     f2bits(er.z * acc.z), f2bits(er.w * acc.w));
  }
  __syncthreads();                 // tile complete across the 4 waves

  // ---- phase 2: wave wv computes t=wv slice: 16 rows x 16 cols ----
  float4v acc2 = (float4v){0.f, 0.f, 0.f, 0.f};
#pragma unroll
  for (int s2 = 0; s2 < 4; ++s2) {
    short8 A = *(const short8*)(tile + (size_t)ln * 136 + s2 * 32 + quad * 8);
    short8 Bf = *(const short8*)(wf + ((size_t)((wv * 4 + s2) * 64 + lane)) * 8);
    acc2 = __builtin_amdgcn_mfma_f32_16x16x32_bf16(A, Bf, acc2, 0, 0, 0);
  }
  int r0 = tg * 16;
  float bt = biasws[layer * 64 + wv * 16 + ln];
#pragma unroll
  for (int g2 = 0; g2 < 4; ++g2) {
    float x = acc2[g2] + bt;
    x = fmaxf(x, 0.2f * x);        // leaky_relu(0.2)
    size_t idx = (size_t)(r0 + quad * 4 + g2) * 64 + wv * 16 + ln;
    ego32_o[idx] = x;
    egobf_o[idx] = f2bits(x);
  }
}

// gather 8192 output rows into out slice; optional l2-normalize per row.
__global__ void k_gather(const float* __restrict__ ego, const int* __restrict__ users,
                         const int* __restrict__ items, void* __restrict__ out,
                         int slice, int do_norm, const int* __restrict__ flag) {
  int f32 = *flag;
  int b = blockIdx.x * 4 + (threadIdx.x >> 6);
  int lane = threadIdx.x & 63;
  if (b >= 8192) return;
  int r = (b < 4096) ? users[b] : (N_USER + items[b - 4096]);
  float x = ego[(size_t)r * D + lane];
  float scale = 1.f;
  if (do_norm) {
    float ss = x * x;
    for (int off = 32; off > 0; off >>= 1) ss += __shfl_xor(ss, off);
    scale = 1.f / fmaxf(sqrtf(ss), 1e-12f);
  }
  float y = x * scale;
  long idx = (long)b * 256 + slice * 64 + lane;
  if (f32) ((float*)out)[idx] = y;
  else ((bf16*)out)[idx] = __float2bfloat16(y);
}

extern "C" void kernel_launch(void* const* d_in, const int* in_sizes, int n_in,
                              void* d_out, int out_size, void* d_ws, size_t ws_size,
                              hipStream_t stream) {
  const void* ue = d_in[0];
  const void* ie = d_in[1];
  const void* Wgc = d_in[2];
  const void* bgc = d_in[3];
  const void* Wbi = d_in[4];
  const void* bbi = d_in[5];
  const void* aval = d_in[6];
  const int* arow = (const int*)d_in[7];
  const int* acol = (const int*)d_in[8];
  const int* users = (const int*)d_in[9];
  const int* items = (const int*)d_in[10];

  char* ws = (char*)d_ws;
  size_t off = 0;
  float* ego32a = (float*)(ws + off); off += (size_t)N_NODES * D * 4;     // 38.4 MB
  u16* egobfa = (u16*)(ws + off);     off += (size_t)N_NODES * D * 2;     // 19.2 MB
  float* ego32b = (float*)(ws + off); off += (size_t)N_NODES * D * 4;     // 38.4 MB
  u16* egobfb = (u16*)(ws + off);     off += (size_t)N_NODES * D * 2;     // 19.2 MB
  int2* staged = (int2*)(ws + off);   off += (size_t)NBUCK * BCAP * 8;    // 42.0 MB
  int2* csr = (int2*)(ws + off);      off += (size_t)STG1 * 8;            // 39.4 MB (aliases level-1 staging)
  int* rp = (int*)(ws + off);         off += (size_t)(N_NODES + 64) * 4;
  int* bcnt = (int*)(ws + off);       off += (size_t)NBUCK * 4;
  int* scnt = (int*)(ws + off);       off += 64 * 4;                      // contiguous after bcnt
  int* bbase = (int*)(ws + off);      off += (size_t)(NBUCK + 64) * 4;
  int* flag = (int*)(ws + off);       off += 256;
  u16* wfrag = (u16*)(ws + off);      off += 3 * 8192 * 2;                // 48 KB frag-ordered weights
  float* biasws = (float*)(ws + off); off += 3 * 64 * 4;                  // combined bias
  int2* staged1 = csr;                // level-1 staging aliases csr (dead until sortbucket)
  (void)ws_size;

  k_zero<<<1, 64, 0, stream>>>(flag, 1);
  k_detect<<<1, 256, 0, stream>>>((const u16*)ue, flag);
  k_zero<<<(NBUCK + 64 + 255) / 256, 256, 0, stream>>>(bcnt, NBUCK + 64);  // bcnt + scnt
  k_prepw<<<3, 512, 0, stream>>>(Wgc, bgc, Wbi, bbi, wfrag, biasws, flag);
  k_init<<<(N_NODES * D / 4 + 255) / 256, 256, 0, stream>>>(ue, ie, ego32a, egobfa, flag);
  // slice 0 = raw (un-normalized) initial ego
  k_gather<<<2048, 256, 0, stream>>>(ego32a, users, items, d_out, 0, 0, flag);
  k_bin1<<<B1, 512, 0, stream>>>(arow, acol, aval, scnt, staged1, flag);
  k_bin2<<<B2, 512, 0, stream>>>(scnt, staged1, bcnt, staged);
  k_bucketbase<<<1, 1024, 0, stream>>>(bcnt, bbase);
  k_sortbucket<<<NBUCK, 512, 0, stream>>>(bcnt, staged, bbase, rp, csr);

  float* ei32 = ego32a; u16* eibf = egobfa;
  float* eo32 = ego32b; u16* eobf = egobfb;
  for (int k = 0; k < 3; ++k) {
    k_layer<<<NG, 256, 0, stream>>>(rp, csr, eibf, ei32, wfrag, biasws,
                                    eo32, eobf, k);
    k_gather<<<2048, 256, 0, stream>>>(eo32, users, items, d_out, k + 1, 1, flag);
    float* t32 = ei32; ei32 = eo32; eo32 = t32;
    u16* tbf = eibf; eibf = eobf; eobf = tbf;
  }
}

// Round 10
// 520.755 us; speedup vs baseline: 1.4653x; 1.0125x over previous
//
#include <hip/hip_runtime.h>
#include <hip/hip_bf16.h>

// NGCF forward on MI355X.
// r17: clean-round CSR-build grids + prod-from-bf16. History:
//  r12 fused 1 tile/wave, weights in L2                         -> 571 (119us/layer)
//  r13 nt hints / r14 hand pipeline / r15 persistent            -> REGRESS (spills; compiler
//      already fine-schedules -- stop touching the inner loop)
//  r16 fine-grain: 1 tile per 4-wave block, grid 9375           -> 527 BEST (102us/layer,
//      occ 80%, FETCH 298/WRITE 56 -- no spill)
// r17 (two independent, separately-diagnosable changes):
//  (a) CSR-build tail fix: bin1/bin2 ran 1172/1221 blocks vs 1024 resident
//      capacity -> 1.14 rounds = ~57% util on uniform blocks. CH1=4688 ->
//      B1=1024 EXACTLY (38.1KB LDS x4 = 152KB/CU ok); CH2=4931, CPS=27 ->
//      B2=999 ~ one clean round. sortbucket left as-is (bucket granularity
//      fixed by SUPSH alignment).
//  (b) k_layer prod = bf16(ego)*side instead of fp32(ego)*side: the A-frag
//      is bf16-rounded right after, and within-row edge order is ALREADY
//      nondeterministic (atomic-cursor scatter in build; absmax pinned at
//      2^-8 across 9 rounds) -> one extra <=1ulp rounding pre-MFMA is safe.
//      Kills the 38.4MB/layer ego32_i read (FETCH 298->~260MB).
// CSR build (r8/r9): two-level bucket binning with LDS repack, int4 edge
// loads, reservation-atomic latency hidden.

#define N_USER 100000
#define N_ITEM 50000
#define N_NODES 150000
#define NE 4800000
#define D 64
#define BROWS 128
#define NBUCK ((N_NODES + BROWS - 1) / BROWS)  // 1172
#define BCAP 4480                               // per-bucket: mean 4096 + 6 sigma
#define NG (N_NODES / 16)                       // 9375 row-tiles of 16 (exact)

// two-level binning
#define SUPSH 12                                // super = row >> 12 (4096 rows)
#define NSUP 37
#define SCAP 133120                             // per-super: mean 131072 + ~5.7 sigma
#define STG1 (NSUP * SCAP)                      // 4,925,440 >= NE
#define CH1 4688                                // edges per bin1 block -> B1 = 1024 EXACT
#define B1 ((NE + CH1 - 1) / CH1)               // 1024 = one clean resident round
#define CPS 27                                  // chunks per super (bin2)
#define CH2 4931                                // 27*4931 = 133137 >= SCAP
#define B2 (NSUP * CPS)                         // 999 blocks ~ one clean round

typedef __hip_bfloat16 bf16;
typedef unsigned short u16;
typedef __attribute__((ext_vector_type(8))) short short8;
typedef __attribute__((ext_vector_type(4))) float float4v;

__device__ __forceinline__ float bits2f(u16 u) {
  return __uint_as_float(((unsigned int)u) << 16);
}
__device__ __forceinline__ u16 f2bits(float x) {
  union { bf16 h; u16 u; } c;
  c.h = __float2bfloat16(x);
  return c.u;
}
__device__ __forceinline__ float loadF(const void* p, long i, int f32) {
  if (f32) return ((const float*)p)[i];
  return bits2f(((const u16*)p)[i]);
}

__global__ void k_zero(int* __restrict__ p, int n) {
  int i = blockIdx.x * blockDim.x + threadIdx.x;
  if (i < n) p[i] = 0;
}

// flag <- 1 if the float buffers are float32, 0 if bf16.
__global__ void k_detect(const u16* __restrict__ ue, int* __restrict__ flag) {
  int bad = 0;
  for (int t = threadIdx.x; t < 512; t += 256) {
    float f = fabsf(bits2f(ue[t]));
    if (!(f < 1e4f)) bad = 1;  // catches NaN/Inf too
  }
  if (bad) atomicOr(flag, 1);
}

// Pre-pack frag-ordered bf16 weights (one block per layer) + combined bias.
// wfrag[layer][f]: f = ((t*4+s2)*64+lane)*8+j maps to W[k][n],
// k = s2*32+(lane>>4)*8+j (in [Wgc;Wbi]), n = t*16+(lane&15).
__global__ void k_prepw(const void* __restrict__ Wgc, const void* __restrict__ bgc,
                        const void* __restrict__ Wbi, const void* __restrict__ bbi,
                        u16* __restrict__ wfrag, float* __restrict__ biasws,
                        const int* __restrict__ flag) {
  int f32 = *flag;
  int layer = blockIdx.x;
  for (int f = threadIdx.x; f < 8192; f += 512) {
    int j = f & 7;
    int lane = (f >> 3) & 63;
    int s2 = (f >> 9) & 3;
    int t = f >> 11;
    int k = s2 * 32 + (lane >> 4) * 8 + j;
    int n = t * 16 + (lane & 15);
    float w = (k < 64) ? loadF(Wgc, (long)layer * 4096 + k * 64 + n, f32)
                       : loadF(Wbi, (long)layer * 4096 + (k - 64) * 64 + n, f32);
    wfrag[layer * 8192 + f] = f2bits(w);
  }
  if (threadIdx.x < 64)
    biasws[layer * 64 + threadIdx.x] =
        loadF(bgc, layer * 64 + threadIdx.x, f32) +
        loadF(bbi, layer * 64 + threadIdx.x, f32);
}

// ego32[N,64] fp32 and egobf[N,64] bf16 <- concat(user_emb, item_emb)
__global__ void k_init(const void* __restrict__ ue, const void* __restrict__ ie,
                       float* __restrict__ ego32, u16* __restrict__ egobf,
                       const int* __restrict__ flag) {
  int f32 = *flag;
  int i4 = (blockIdx.x * blockDim.x + threadIdx.x) * 4;
  if (i4 >= N_NODES * D) return;
  const int UD = N_USER * D;
  float4 v;
  ushort4 b;
  if (f32) {
    const float* s = (i4 < UD) ? ((const float*)ue + i4) : ((const float*)ie + (i4 - UD));
    v = *(const float4*)s;
    b = make_ushort4(f2bits(v.x), f2bits(v.y), f2bits(v.z), f2bits(v.w));
  } else {
    const u16* s = (i4 < UD) ? ((const u16*)ue + i4) : ((const u16*)ie + (i4 - UD));
    b = *(const ushort4*)s;
    v = make_float4(bits2f(b.x), bits2f(b.y), bits2f(b.z), bits2f(b.w));
  }
  *(float4*)(ego32 + i4) = v;
  *(ushort4*)(egobf + i4) = b;
}

// Level 1: bin a CH1-edge chunk into NSUP super-buckets. Scatter into LDS
// (counting-sort order by super), then write each super's run coalesced into
// staged1[super][SCAP]. Entry: (lr12<<18 | col, val_bits), lr12 = row & 4095.
__global__ void __launch_bounds__(512, 8) k_bin1(
    const int* __restrict__ row, const int* __restrict__ col,
    const void* __restrict__ val, int* __restrict__ scnt,
    int2* __restrict__ staged1, const int* __restrict__ flag) {
  __shared__ int2 sbuf[CH1];                 // 36.6 KB
  __shared__ int hist[NSUP];
  __shared__ int lstart[NSUP];
  __shared__ int gbase[NSUP];
  __shared__ int lcur[NSUP];
  int f32 = *flag;
  int tid = threadIdx.x;
  int e0 = blockIdx.x * CH1;
  int e1 = min(e0 + CH1, NE);               // e1-e0 always a multiple of 4
  if (tid < NSUP) hist[tid] = 0;
  __syncthreads();
  // pass 1: histogram over supers, 4 edges/thread (int4)
  for (int e = e0 + tid * 4; e < e1; e += 512 * 4) {
    int4 r4 = *(const int4*)(row + e);
    atomicAdd(&hist[r4.x >> SUPSH], 1);
    atomicAdd(&hist[r4.y >> SUPSH], 1);
    atomicAdd(&hist[r4.z >> SUPSH], 1);
    atomicAdd(&hist[r4.w >> SUPSH], 1);
  }
  __syncthreads();
  // wave 0: exclusive scan of hist; issue the global reservation atomic into
  // a register (committed to LDS only after the scatter -> latency hidden)
  int resv = 0;
  if (tid < 64) {
    int h = (tid < NSUP) ? hist[tid] : 0;
    int inc = h;
#pragma unroll
    for (int off = 1; off < 64; off <<= 1) {
      int v = __shfl_up(inc, off);
      if (tid >= off) inc += v;
    }
    if (tid < NSUP) {
      int ex = inc - h;
      lstart[tid] = ex;
      lcur[tid] = ex;
      if (h) resv = atomicAdd(&scnt[tid], h);
    }
  }
  __syncthreads();
  // pass 2: scatter into LDS in super-sorted order, 4 edges/thread
  for (int e = e0 + tid * 4; e < e1; e += 512 * 4) {
    int4 r4 = *(const int4*)(row + e);
    int4 c4 = *(const int4*)(col + e);
    int vb[4];
    if (f32) {
      float4 v4 = *(const float4*)((const float*)val + e);
      vb[0] = __float_as_int(v4.x); vb[1] = __float_as_int(v4.y);
      vb[2] = __float_as_int(v4.z); vb[3] = __float_as_int(v4.w);
    } else {
      ushort4 v4 = *(const ushort4*)((const u16*)val + e);
      vb[0] = __float_as_int(bits2f(v4.x)); vb[1] = __float_as_int(bits2f(v4.y));
      vb[2] = __float_as_int(bits2f(v4.z)); vb[3] = __float_as_int(bits2f(v4.w));
    }
    int rr[4] = {r4.x, r4.y, r4.z, r4.w};
    int cc[4] = {c4.x, c4.y, c4.z, c4.w};
#pragma unroll
    for (int j = 0; j < 4; ++j) {
      int s = rr[j] >> SUPSH;
      int pos = atomicAdd(&lcur[s], 1);
      sbuf[pos] = make_int2(((rr[j] & 4095) << 18) | cc[j], vb[j]);
    }
  }
  // commit reservations (atomic result consumed here, after scatter)
  if (tid < NSUP) gbase[tid] = resv;
  __syncthreads();
  // coalesced dense copy of each super's run; waves split the supers
  int wv = tid >> 6;
  int ln = tid & 63;
  for (int s = wv; s < NSUP; s += 8) {
    int h = hist[s];
    int gb = gbase[s];
    int ls = lstart[s];
    if (gb + h > SCAP) h = max(0, SCAP - gb);
    int2* dst = staged1 + (size_t)s * SCAP + gb;
    for (int i = ln; i < h; i += 64) dst[i] = sbuf[ls + i];
  }
}

// Level 2: re-bin one CH2-entry chunk of a super segment into its 32 row-
// buckets (global bucket = super*32 + (lr12>>7)), LDS repack, coalesced dense
// write into staged2[bucket][BCAP]. Output entry: (lr7<<18 | col, val_bits).
__global__ void __launch_bounds__(512, 8) k_bin2(
    const int* __restrict__ scnt, const int2* __restrict__ staged1,
    int* __restrict__ bcnt, int2* __restrict__ staged2) {
  __shared__ int2 sbuf[CH2];                 // 38.5 KB
  __shared__ int hist[32];
  __shared__ int lstart[32];
  __shared__ int gbase[32];
  __shared__ int lcur[32];
  int tid = threadIdx.x;
  int sup = blockIdx.x / CPS;
  int e0 = (blockIdx.x % CPS) * CH2;
  int n = min(scnt[sup], SCAP);
  int e1 = min(e0 + CH2, n);
  if (e0 >= e1) return;  // uniform across block
  const int2* seg = staged1 + (size_t)sup * SCAP;
  if (tid < 32) hist[tid] = 0;
  __syncthreads();
  // histogram, 2 entries/thread (int4 over int2 pairs); e1 may be odd
  {
    int e = e0 + tid * 2;
    for (; e + 1 < e1; e += 1024) {
      int4 two = *(const int4*)(seg + e);
      atomicAdd(&hist[two.x >> 25], 1);
      atomicAdd(&hist[two.z >> 25], 1);
    }
    if (e < e1) atomicAdd(&hist[seg[e].x >> 25], 1);
  }
  __syncthreads();
  int resv = 0;
  if (tid < 64) {
    int h = (tid < 32) ? hist[tid & 31] : 0;
    int inc = h;
#pragma unroll
    for (int off = 1; off < 32; off <<= 1) {
      int v = __shfl_up(inc, off);
      if (tid >= off) inc += v;
    }
    if (tid < 32) {
      int ex = inc - h;
      lstart[tid] = ex;
      lcur[tid] = ex;
      if (h) resv = atomicAdd(&bcnt[sup * 32 + tid], h);
    }
  }
  __syncthreads();
  // scatter into LDS in bucket-sorted order, 2 entries/thread
  {
    int e = e0 + tid * 2;
    for (; e + 1 < e1; e += 1024) {
      int4 two = *(const int4*)(seg + e);
      int lb0 = two.x >> 25;
      int p0 = atomicAdd(&lcur[lb0], 1);
      sbuf[p0] = make_int2(two.x & 0x01FFFFFF, two.y);
      int lb1 = two.z >> 25;
      int p1 = atomicAdd(&lcur[lb1], 1);
      sbuf[p1] = make_int2(two.z & 0x01FFFFFF, two.w);
    }
    if (e < e1) {
      int2 ent = seg[e];
      int lb = ent.x >> 25;
      int pos = atomicAdd(&lcur[lb], 1);
      sbuf[pos] = make_int2(ent.x & 0x01FFFFFF, ent.y);
    }
  }
  if (tid < 32) gbase[tid] = resv;
  __syncthreads();
  // coalesced dense copy of each bucket's run; waves split the buckets
  int wv = tid >> 6;
  int ln = tid & 63;
  for (int lb = wv; lb < 32; lb += 8) {
    int h = hist[lb];
    int gb = gbase[lb];
    int ls = lstart[lb];
    int b = sup * 32 + lb;
    if (b >= NBUCK) continue;       // unreachable given row bounds; safety
    if (gb + h > BCAP) h = max(0, BCAP - gb);
    int2* dst = staged2 + (size_t)b * BCAP + gb;
    for (int i = ln; i < h; i += 64) dst[i] = sbuf[ls + i];
  }
}

// Exclusive scan of per-bucket totals -> bbase[NBUCK]. One block of 1024.
__global__ void __launch_bounds__(1024) k_bucketbase(const int* __restrict__ bcnt,
                                                     int* __restrict__ bbase) {
  __shared__ int sh[2048];
  int tid = threadIdx.x;
  int t0 = (tid < NBUCK) ? min(bcnt[tid], BCAP) : 0;
  int i1 = 1024 + tid;
  int t1 = (i1 < NBUCK) ? min(bcnt[i1], BCAP) : 0;
  sh[tid] = t0;
  sh[i1] = t1;
  __syncthreads();
  for (int off = 1; off < 2048; off <<= 1) {
    int a0 = (tid >= off) ? sh[tid - off] : 0;
    int a1 = (i1 >= off) ? sh[i1 - off] : 0;
    __syncthreads();
    sh[tid] += a0;
    sh[i1] += a1;
    __syncthreads();
  }
  if (tid < NBUCK) bbase[tid] = sh[tid] - t0;       // exclusive
  if (i1 < NBUCK) bbase[i1] = sh[i1] - t1;
}

// One block per bucket: LDS counting sort of the bucket's staged edges, then
// coalesced sequential write of the contiguous CSR segment + rp.
__global__ void __launch_bounds__(512, 8) k_sortbucket(
    const int* __restrict__ bcnt, const int2* __restrict__ staged,
    const int* __restrict__ bbase, int* __restrict__ rp, int2* __restrict__ csr) {
  __shared__ int2 sbuf[BCAP];      // 35.8 KB
  __shared__ int hist[BROWS];
  __shared__ int cursor[BROWS];
  __shared__ int scantmp[BROWS];
  int tid = threadIdx.x;
  int b = blockIdx.x;
  if (tid < BROWS) hist[tid] = 0;
  __syncthreads();

  int n = min(bcnt[b], BCAP);
  const int2* seg = staged + (size_t)b * BCAP;
  {
    int e = tid * 2;
    for (; e + 1 < n; e += 1024) {
      int4 two = *(const int4*)(seg + e);
      atomicAdd(&hist[two.x >> 18], 1);
      atomicAdd(&hist[two.z >> 18], 1);
    }
    if (e < n) atomicAdd(&hist[seg[e].x >> 18], 1);
  }
  __syncthreads();

  if (tid < BROWS) scantmp[tid] = hist[tid];
  __syncthreads();
  for (int off = 1; off < BROWS; off <<= 1) {
    int v = (tid < BROWS && tid >= off) ? scantmp[tid - off] : 0;
    __syncthreads();
    if (tid < BROWS) scantmp[tid] += v;   // inclusive
    __syncthreads();
  }
  int base_b = bbase[b];
  if (tid < BROWS) {
    int ex = scantmp[tid] - hist[tid];    // exclusive start within bucket
    cursor[tid] = ex;
    int r = b * BROWS + tid;
    if (r < N_NODES) rp[r] = base_b + ex;
  }
  if (b == 0 && tid == 0) rp[N_NODES] = NE;
  __syncthreads();

  {
    int e = tid * 2;
    for (; e + 1 < n; e += 1024) {
      int4 two = *(const int4*)(seg + e);
      int lr0 = two.x >> 18;
      int p0 = atomicAdd(&cursor[lr0], 1);
      if (p0 < BCAP) sbuf[p0] = make_int2(two.x & 0x3FFFF, two.y);
      int lr1 = two.z >> 18;
      int p1 = atomicAdd(&cursor[lr1], 1);
      if (p1 < BCAP) sbuf[p1] = make_int2(two.z & 0x3FFFF, two.w);
    }
    if (e < n) {
      int2 ent = seg[e];
      int lr = ent.x >> 18;
      int pos = atomicAdd(&cursor[lr], 1);
      if (pos < BCAP) sbuf[pos] = make_int2(ent.x & 0x3FFFF, ent.y);
    }
  }
  __syncthreads();

  int tot = min(scantmp[BROWS - 1], BCAP);
  for (int i = tid; i < tot; i += 512) csr[(size_t)base_b + i] = sbuf[i];
}

// FUSED layer (r17 = r16 structure): ONE 16-row tile per 4-wave 256-thread
// block. Wave wv runs SpMM pass p=wv (rows tg*16 + wv*4 + quad; 16 lanes
// consume full 128B neighbor rows, csr broadcast within quarter-wave),
// depositing bf16 [side|prod] into the block-shared LDS tile (272B row
// stride -> <=2-way bank alias, free). prod now sourced from egobf_i (bf16)
// -- kills the 38.4MB/layer ego32_i stream; one extra <=1ulp rounding
// pre-MFMA (safe: A-frag is bf16 anyway, edge order already nondet).
// __syncthreads, then wave wv computes its t=wv column-slice: 4 MFMAs
// (B-frags 16B global loads from L2-resident wfrag), writes cols
// [wv*16,+16).
__global__ void __launch_bounds__(256, 8) k_layer(
    const int* __restrict__ rp, const int2* __restrict__ csr,
    const u16* __restrict__ egobf_i,
    const u16* __restrict__ wfrag, const float* __restrict__ biasws,
    float* __restrict__ ego32_o, u16* __restrict__ egobf_o, int layer) {
  __shared__ u16 tile[2176];       // 16 rows x 136 u16 (272B stride), 4.25KB
  int tid = threadIdx.x;
  int lane = tid & 63;
  int ln = lane & 15;
  int quad = lane >> 4;            // 0..3
  int wv = tid >> 6;               // 0..3 = SpMM pass index = MFMA t-slice
  int tg = blockIdx.x;             // tile index (16 rows); grid == NG
  const u16* wf = wfrag + layer * 8192;

  // ---- phase 1: SpMM pass wv (4 rows, quarter-wave per row) ----
  {
    int r = tg * 16 + wv * 4 + quad;
    int s = rp[r];
    int e = rp[r + 1];
    float4 acc = make_float4(0.f, 0.f, 0.f, 0.f);
    int i = s;
    for (; i + 8 <= e; i += 8) {
      int2 cc[8];
#pragma unroll
      for (int t = 0; t < 8; ++t) cc[t] = csr[i + t];
      ushort4 gg[8];
#pragma unroll
      for (int t = 0; t < 8; ++t)
        gg[t] = *(const ushort4*)(egobf_i + (size_t)cc[t].x * 64 + ln * 4);
#pragma unroll
      for (int t = 0; t < 8; ++t) {
        float v = __int_as_float(cc[t].y);
        acc.x += v * bits2f(gg[t].x);
        acc.y += v * bits2f(gg[t].y);
        acc.z += v * bits2f(gg[t].z);
        acc.w += v * bits2f(gg[t].w);
      }
    }
    for (; i < e; ++i) {
      int2 c = csr[i];
      ushort4 g = *(const ushort4*)(egobf_i + (size_t)c.x * 64 + ln * 4);
      float v = __int_as_float(c.y);
      acc.x += v * bits2f(g.x);
      acc.y += v * bits2f(g.y);
      acc.z += v * bits2f(g.z);
      acc.w += v * bits2f(g.w);
    }
    // own-row ego from bf16 (kills the fp32 ego32_i stream)
    ushort4 eb = *(const ushort4*)(egobf_i + (size_t)r * 64 + ln * 4);
    float4 er = make_float4(bits2f(eb.x), bits2f(eb.y), bits2f(eb.z), bits2f(eb.w));
    // deposit [side|prod] into shared tile row (wv*4+quad)
    u16* trow = tile + (wv * 4 + quad) * 136;
    *(ushort4*)(trow + ln * 4) =
        make_ushort4(f2bits(acc.x), f2bits(acc.y), f2bits(acc.z), f2bits(acc.w));
    *(ushort4*)(trow + 64 + ln * 4) =
        make_ushort4(f2bits(er.x * acc.x), f2bits(er.y * acc.y),
                     f2bits(er.z * acc.z), f2bits(er.w * acc.w));
  }
  __syncthreads();                 // tile complete across the 4 waves

  // ---- phase 2: wave wv computes t=wv slice: 16 rows x 16 cols ----
  float4v acc2 = (float4v){0.f, 0.f, 0.f, 0.f};
#pragma unroll
  for (int s2 = 0; s2 < 4; ++s2) {
    short8 A = *(const short8*)(tile + (size_t)ln * 136 + s2 * 32 + quad * 8);
    short8 Bf = *(const short8*)(wf + ((size_t)((wv * 4 + s2) * 64 + lane)) * 8);
    acc2 = __builtin_amdgcn_mfma_f32_16x16x32_bf16(A, Bf, acc2, 0, 0, 0);
  }
  int r0 = tg * 16;
  float bt = biasws[layer * 64 + wv * 16 + ln];
#pragma unroll
  for (int g2 = 0; g2 < 4; ++g2) {
    float x = acc2[g2] + bt;
    x = fmaxf(x, 0.2f * x);        // leaky_relu(0.2)
    size_t idx = (size_t)(r0 + quad * 4 + g2) * 64 + wv * 16 + ln;
    ego32_o[idx] = x;
    egobf_o[idx] = f2bits(x);
  }
}

// gather 8192 output rows into out slice; optional l2-normalize per row.
__global__ void k_gather(const float* __restrict__ ego, const int* __restrict__ users,
                         const int* __restrict__ items, void* __restrict__ out,
                         int slice, int do_norm, const int* __restrict__ flag) {
  int f32 = *flag;
  int b = blockIdx.x * 4 + (threadIdx.x >> 6);
  int lane = threadIdx.x & 63;
  if (b >= 8192) return;
  int r = (b < 4096) ? users[b] : (N_USER + items[b - 4096]);
  float x = ego[(size_t)r * D + lane];
  float scale = 1.f;
  if (do_norm) {
    float ss = x * x;
    for (int off = 32; off > 0; off >>= 1) ss += __shfl_xor(ss, off);
    scale = 1.f / fmaxf(sqrtf(ss), 1e-12f);
  }
  float y = x * scale;
  long idx = (long)b * 256 + slice * 64 + lane;
  if (f32) ((float*)out)[idx] = y;
  else ((bf16*)out)[idx] = __float2bfloat16(y);
}

extern "C" void kernel_launch(void* const* d_in, const int* in_sizes, int n_in,
                              void* d_out, int out_size, void* d_ws, size_t ws_size,
                              hipStream_t stream) {
  const void* ue = d_in[0];
  const void* ie = d_in[1];
  const void* Wgc = d_in[2];
  const void* bgc = d_in[3];
  const void* Wbi = d_in[4];
  const void* bbi = d_in[5];
  const void* aval = d_in[6];
  const int* arow = (const int*)d_in[7];
  const int* acol = (const int*)d_in[8];
  const int* users = (const int*)d_in[9];
  const int* items = (const int*)d_in[10];

  char* ws = (char*)d_ws;
  size_t off = 0;
  float* ego32a = (float*)(ws + off); off += (size_t)N_NODES * D * 4;     // 38.4 MB
  u16* egobfa = (u16*)(ws + off);     off += (size_t)N_NODES * D * 2;     // 19.2 MB
  float* ego32b = (float*)(ws + off); off += (size_t)N_NODES * D * 4;     // 38.4 MB
  u16* egobfb = (u16*)(ws + off);     off += (size_t)N_NODES * D * 2;     // 19.2 MB
  int2* staged = (int2*)(ws + off);   off += (size_t)NBUCK * BCAP * 8;    // 42.0 MB
  int2* csr = (int2*)(ws + off);      off += (size_t)STG1 * 8;            // 39.4 MB (aliases level-1 staging)
  int* rp = (int*)(ws + off);         off += (size_t)(N_NODES + 64) * 4;
  int* bcnt = (int*)(ws + off);       off += (size_t)NBUCK * 4;
  int* scnt = (int*)(ws + off);       off += 64 * 4;                      // contiguous after bcnt
  int* bbase = (int*)(ws + off);      off += (size_t)(NBUCK + 64) * 4;
  int* flag = (int*)(ws + off);       off += 256;
  u16* wfrag = (u16*)(ws + off);      off += 3 * 8192 * 2;                // 48 KB frag-ordered weights
  float* biasws = (float*)(ws + off); off += 3 * 64 * 4;                  // combined bias
  int2* staged1 = csr;                // level-1 staging aliases csr (dead until sortbucket)
  (void)ws_size;

  k_zero<<<1, 64, 0, stream>>>(flag, 1);
  k_detect<<<1, 256, 0, stream>>>((const u16*)ue, flag);
  k_zero<<<(NBUCK + 64 + 255) / 256, 256, 0, stream>>>(bcnt, NBUCK + 64);  // bcnt + scnt
  k_prepw<<<3, 512, 0, stream>>>(Wgc, bgc, Wbi, bbi, wfrag, biasws, flag);
  k_init<<<(N_NODES * D / 4 + 255) / 256, 256, 0, stream>>>(ue, ie, ego32a, egobfa, flag);
  // slice 0 = raw (un-normalized) initial ego
  k_gather<<<2048, 256, 0, stream>>>(ego32a, users, items, d_out, 0, 0, flag);
  k_bin1<<<B1, 512, 0, stream>>>(arow, acol, aval, scnt, staged1, flag);
  k_bin2<<<B2, 512, 0, stream>>>(scnt, staged1, bcnt, staged);
  k_bucketbase<<<1, 1024, 0, stream>>>(bcnt, bbase);
  k_sortbucket<<<NBUCK, 512, 0, stream>>>(bcnt, staged, bbase, rp, csr);

  float* ei32 = ego32a; u16* eibf = egobfa;
  float* eo32 = ego32b; u16* eobf = egobfb;
  for (int k = 0; k < 3; ++k) {
    k_layer<<<NG, 256, 0, stream>>>(rp, csr, eibf, wfrag, biasws,
                                    eo32, eobf, k);
    k_gather<<<2048, 256, 0, stream>>>(eo32, users, items, d_out, k + 1, 1, flag);
    float* t32 = ei32; ei32 = eo32; eo32 = t32;
    u16* tbf = eibf; eibf = eobf; eobf = tbf;
  }
}